// Round 1
// baseline (301.846 us; speedup 1.0000x reference)
//
#include <hip/hip_runtime.h>
#include <hip/hip_bf16.h>
#include <math.h>

#define B_ 32
#define C_ 2048
#define HW_ 576          // 24*24
#define P_ 4
#define HID_ 128         // C/RED

// ---------------- pool: pooled[b,c] = mean_hw x[b,c,hw] ----------------
// one wave per (b,c) row of 576 floats (144 float4), 4 waves/block
__global__ void pool_kernel(const float* __restrict__ x, float* __restrict__ pooled) {
    int gwave = blockIdx.x * 4 + (threadIdx.x >> 6);   // [0, 65536)
    int lane  = threadIdx.x & 63;
    const float4* xp4 = (const float4*)(x + (size_t)gwave * HW_);
    float s = 0.f;
    for (int i = lane; i < HW_ / 4; i += 64) {         // 144 float4
        float4 v = xp4[i];
        s += v.x + v.y + v.z + v.w;
    }
    #pragma unroll
    for (int off = 32; off > 0; off >>= 1) s += __shfl_down(s, off, 64);
    if (lane == 0) pooled[gwave] = s * (1.0f / (float)HW_);
}

// ---------------- fc1: hidden[b,j] = silu(pooled[b,:]·fc1_w[j,:] + b1[j]) ----------------
// one wave per output (32*128 = 4096 outputs), 4 waves/block -> 1024 blocks
__global__ void fc1_kernel(const float* __restrict__ pooled, const float* __restrict__ w,
                           const float* __restrict__ bias, float* __restrict__ hidden) {
    int o    = blockIdx.x * 4 + (threadIdx.x >> 6);    // [0, 4096)
    int lane = threadIdx.x & 63;
    int b = o >> 7;        // /128
    int j = o & 127;
    const float* pr = pooled + (size_t)b * C_;
    const float* wr = w + (size_t)j * C_;
    float s = 0.f;
    for (int k = lane; k < C_; k += 64) s += pr[k] * wr[k];
    #pragma unroll
    for (int off = 32; off > 0; off >>= 1) s += __shfl_down(s, off, 64);
    if (lane == 0) {
        float z = s + bias[j];
        hidden[o] = z / (1.0f + expf(-z));             // silu
    }
}

// ---------------- fc2: dw[b,o] = hidden[b,:]·fc2_w[o,:] + b2[o] ----------------
// one wave per output (32*8192 = 262144 outputs), 4 waves/block -> 65536 blocks
__global__ void fc2_kernel(const float* __restrict__ hidden, const float* __restrict__ w,
                           const float* __restrict__ bias, float* __restrict__ dw) {
    int o    = blockIdx.x * 4 + (threadIdx.x >> 6);    // [0, 262144)
    int lane = threadIdx.x & 63;
    int b = o >> 13;       // /8192
    int j = o & 8191;
    const float* hr = hidden + (size_t)b * HID_;
    const float* wr = w + (size_t)j * HID_;
    float s = hr[lane] * wr[lane] + hr[lane + 64] * wr[lane + 64];
    #pragma unroll
    for (int off = 32; off > 0; off >>= 1) s += __shfl_down(s, off, 64);
    if (lane == 0) dw[o] = s + bias[j];
}

// ---------------- bias_const[b,p] = sum_c conv_b[c]*dw[b,p,c] ----------------
// one wave per (b,p) (128 outputs), 4 waves/block -> 32 blocks
__global__ void biasc_kernel(const float* __restrict__ conv_b, const float* __restrict__ dw,
                             float* __restrict__ bias_const) {
    int o    = blockIdx.x * 4 + (threadIdx.x >> 6);    // [0, 128) == b*4+p
    int lane = threadIdx.x & 63;
    const float* dr = dw + (size_t)o * C_;
    float s = 0.f;
    for (int k = lane; k < C_; k += 64) s += conv_b[k] * dr[k];
    #pragma unroll
    for (int off = 32; off > 0; off >>= 1) s += __shfl_down(s, off, 64);
    if (lane == 0) bias_const[o] = s;
}

// ---------------- einsum: accum[b,p,hw] += sum_{c in chunk} x[b,c,hw]*(conv_w[c]*dw[b,p,c]) ----------------
// grid (b=32, chunk=32), 64 channels per chunk, 576 threads = one per hw
__global__ void einsum_kernel(const float* __restrict__ x, const float* __restrict__ conv_w,
                              const float* __restrict__ dw, float* __restrict__ accum) {
    int b     = blockIdx.x;
    int chunk = blockIdx.y;
    int c0    = chunk * 64;
    int tid   = threadIdx.x;                           // [0, 576)

    __shared__ float4 m4[64];                          // m4[c] = {cw*dw[p=0..3]}
    if (tid < 64) {
        float cw = conv_w[c0 + tid];
        const float* dr = dw + (size_t)b * (P_ * C_) + c0 + tid;
        float4 v;
        v.x = cw * dr[0 * C_];
        v.y = cw * dr[1 * C_];
        v.z = cw * dr[2 * C_];
        v.w = cw * dr[3 * C_];
        m4[tid] = v;
    }
    __syncthreads();

    const float* xp = x + ((size_t)b * C_ + c0) * HW_ + tid;
    float a0 = 0.f, a1 = 0.f, a2 = 0.f, a3 = 0.f;
    #pragma unroll 8
    for (int c = 0; c < 64; ++c) {
        float v = xp[(size_t)c * HW_];
        float4 m = m4[c];
        a0 += v * m.x;
        a1 += v * m.y;
        a2 += v * m.z;
        a3 += v * m.w;
    }
    float* ap = accum + ((size_t)b * P_) * HW_ + tid;
    atomicAdd(ap + 0 * HW_, a0);
    atomicAdd(ap + 1 * HW_, a1);
    atomicAdd(ap + 2 * HW_, a2);
    atomicAdd(ap + 3 * HW_, a3);
}

// ---------------- softmax over p + write out ----------------
// thread per (b,hw): 18432 threads = 72 blocks * 256
__global__ void softmax_kernel(const float* __restrict__ accum, const float* __restrict__ bias_const,
                               float* __restrict__ out) {
    int idx = blockIdx.x * 256 + threadIdx.x;          // [0, 18432)
    int b  = idx / HW_;
    int hw = idx - b * HW_;
    const float* ap = accum + ((size_t)b * P_) * HW_ + hw;
    const float* bc = bias_const + b * P_;
    float v0 = ap[0 * HW_] + bc[0];
    float v1 = ap[1 * HW_] + bc[1];
    float v2 = ap[2 * HW_] + bc[2];
    float v3 = ap[3 * HW_] + bc[3];
    float mx = fmaxf(fmaxf(v0, v1), fmaxf(v2, v3));
    float e0 = expf(v0 - mx), e1 = expf(v1 - mx), e2 = expf(v2 - mx), e3 = expf(v3 - mx);
    float inv = 1.0f / (e0 + e1 + e2 + e3);
    float* op = out + ((size_t)b * P_) * HW_ + hw;
    op[0 * HW_] = e0 * inv;
    op[1 * HW_] = e1 * inv;
    op[2 * HW_] = e2 * inv;
    op[3 * HW_] = e3 * inv;
}

extern "C" void kernel_launch(void* const* d_in, const int* in_sizes, int n_in,
                              void* d_out, int out_size, void* d_ws, size_t ws_size,
                              hipStream_t stream) {
    const float* x      = (const float*)d_in[0];
    const float* fc1_w  = (const float*)d_in[1];
    const float* fc1_b  = (const float*)d_in[2];
    const float* fc2_w  = (const float*)d_in[3];
    const float* fc2_b  = (const float*)d_in[4];
    const float* conv_w = (const float*)d_in[5];
    const float* conv_b = (const float*)d_in[6];
    float* out = (float*)d_out;

    // workspace layout (floats)
    float* ws      = (float*)d_ws;
    float* pooled  = ws;                    // 32*2048   = 65536
    float* hidden  = pooled + 65536;        // 32*128    = 4096
    float* dw      = hidden + 4096;         // 32*8192   = 262144
    float* bias_c  = dw + 262144;           // 128
    float* accum   = bias_c + 128;          // 32*4*576  = 73728

    hipMemsetAsync(accum, 0, (size_t)B_ * P_ * HW_ * sizeof(float), stream);

    pool_kernel<<<16384, 256, 0, stream>>>(x, pooled);
    fc1_kernel<<<1024, 256, 0, stream>>>(pooled, fc1_w, fc1_b, hidden);
    fc2_kernel<<<65536, 256, 0, stream>>>(hidden, fc2_w, fc2_b, dw);
    biasc_kernel<<<32, 256, 0, stream>>>(conv_b, dw, bias_c);
    einsum_kernel<<<dim3(B_, 32), 576, 0, stream>>>(x, conv_w, dw, accum);
    softmax_kernel<<<72, 256, 0, stream>>>(accum, bias_c, out);
}